// Round 14
// baseline (684.423 us; speedup 1.0000x reference)
//
#include <hip/hip_runtime.h>
#include <hip/hip_cooperative_groups.h>

namespace cg = cooperative_groups;

#define D 64

// ---------------------------------------------------------------------------
// edge_index dtype detection (int32 vs int64), done per-block on device.
// ---------------------------------------------------------------------------
#define DETECT_IS64(ei)                                        \
  __shared__ int s_is64;                                       \
  if (threadIdx.x == 0) {                                      \
    const unsigned int* w_ = (const unsigned int*)(ei);        \
    int is64_ = 1;                                             \
    for (int i_ = 0; i_ < 64; ++i_) {                          \
      if (w_[2 * i_ + 1] != 0u) { is64_ = 0; break; }          \
    }                                                          \
    s_is64 = is64_;                                            \
  }                                                            \
  __syncthreads();

// Fallback-path grid/block (hist & place must match: shard = blockIdx&(S-1)).
#define EDGE_GRID 4096
#define EDGE_BLOCK 256
#define SCAN_CHUNKS 8192

// Cooperative fused-sort geometry: 1024 blocks x 256 thr, 4 blocks/CU
// guaranteed by __launch_bounds__(256,4) -> co-resident on 256 CUs.
#define COOP_BLOCKS 1024
#define COOP_THREADS 256
#define COOP_NT (COOP_BLOCKS * COOP_THREADS)

// ---------------------------------------------------------------------------
// FUSED hist + scan + place (cooperative). Each thread owns up to 7 edges,
// held in REGISTERS across phases (no second edge_index pass):
//   P1 histogram -> sync -> P2 two-level exclusive scan of C (4 elems/thread,
//   block LDS scan, block-0 scans block totals) -> sync -> P3 place.
// shard = blockIdx & (S-1): with round-robin block->XCD dispatch, each
// shard's cursor lines and sorted region stay XCD-local.
// After P3, C[k] = prefix[k+1] (gather contract preserved).
// ---------------------------------------------------------------------------
__global__ __launch_bounds__(256, 4) void gin_fused_sort(
    const void* __restrict__ edge_index, int* __restrict__ C,
    int* __restrict__ bt, int* __restrict__ sorted_src,
    int n_edges, int n_nodes, int nshard, int total) {
  cg::grid_group grid = cg::this_grid();
  DETECT_IS64(edge_index);
  const int* ei32 = (const int*)edge_index;
  const long long* ei64 = (const long long*)edge_index;
  const int t = (int)threadIdx.x;
  const int b = (int)blockIdx.x;
  const int g = b * COOP_THREADS + t;
  int* Cs = C + (size_t)(b & (nshard - 1)) * n_nodes;

  // --- P1: histogram; cache edges in registers (static indexing) ---
  int myDst[7], mySrc[7];
#pragma unroll
  for (int k = 0; k < 7; ++k) {
    const int e = g + k * COOP_NT;  // coalesced per k
    int dst = -1, src = 0;
    if (e < n_edges) {
      if (s_is64) {
        src = (int)ei64[e];
        dst = (int)ei64[n_edges + e];
      } else {
        src = ei32[e];
        dst = ei32[n_edges + e];
      }
      atomicAdd(&Cs[dst], 1);
    }
    myDst[k] = dst;
    mySrc[k] = src;
  }
  grid.sync();

  // --- P2a: per-thread sum of C[4g..4g+4) + LDS exclusive scan over block ---
  __shared__ int ls[COOP_THREADS];
  int cv[4];
  int tsum = 0;
#pragma unroll
  for (int i = 0; i < 4; ++i) {
    const int idx = 4 * g + i;
    cv[i] = (idx < total) ? C[idx] : 0;
    tsum += cv[i];
  }
  ls[t] = tsum;
  __syncthreads();
  for (int o = 1; o < COOP_THREADS; o <<= 1) {
    const int a = (t >= o) ? ls[t - o] : 0;
    __syncthreads();
    ls[t] += a;
    __syncthreads();
  }
  const int excl = ls[t] - tsum;
  if (t == COOP_THREADS - 1) bt[b] = ls[t];
  grid.sync();

  // --- P2b: block 0 scans the COOP_BLOCKS block totals (4/thread) ---
  if (b == 0) {
    int bv[4];
    int bsum = 0;
#pragma unroll
    for (int i = 0; i < 4; ++i) {
      const int idx = 4 * t + i;
      bv[i] = (idx < COOP_BLOCKS) ? bt[idx] : 0;
      bsum += bv[i];
    }
    __syncthreads();
    ls[t] = bsum;
    __syncthreads();
    for (int o = 1; o < COOP_THREADS; o <<= 1) {
      const int a = (t >= o) ? ls[t - o] : 0;
      __syncthreads();
      ls[t] += a;
      __syncthreads();
    }
    int run = ls[t] - bsum;
#pragma unroll
    for (int i = 0; i < 4; ++i) {
      const int idx = 4 * t + i;
      if (idx < COOP_BLOCKS) bt[idx] = run;
      run += bv[i];
    }
  }
  grid.sync();

  // --- P2c: write exclusive prefix back into C (cursor init) ---
  {
    int run = bt[b] + excl;
#pragma unroll
    for (int i = 0; i < 4; ++i) {
      const int idx = 4 * g + i;
      if (idx < total) C[idx] = run;
      run += cv[i];
    }
  }
  grid.sync();

  // --- P3: place from registers (no edge re-read) ---
#pragma unroll
  for (int k = 0; k < 7; ++k) {
    if (myDst[k] >= 0) {
      const int pos = atomicAdd(&Cs[myDst[k]], 1);
      sorted_src[pos] = mySrc[k];
    }
  }
}

// ---------------------------------------------------------------------------
// Fallback kernels (non-cooperative path) — round-6..13 pipeline.
// ---------------------------------------------------------------------------
__global__ __launch_bounds__(256) void gin_hist_sharded(
    const void* __restrict__ edge_index, int* __restrict__ C,
    int n_edges, int n_nodes, int nshard) {
  DETECT_IS64(edge_index);
  const int* ei32 = (const int*)edge_index;
  const long long* ei64 = (const long long*)edge_index;
  int* Cs = C + (size_t)(blockIdx.x & (nshard - 1)) * n_nodes;
  const int i = (int)(blockIdx.x * blockDim.x + threadIdx.x);
  const int stride = (int)(gridDim.x * blockDim.x);
  for (int e = i; e < n_edges; e += stride) {
    const int dst = s_is64 ? (int)ei64[n_edges + e] : ei32[n_edges + e];
    atomicAdd(&Cs[dst], 1);
  }
}

__global__ __launch_bounds__(256) void gin_scan_a(
    const int* __restrict__ C, int* __restrict__ tsum, int total, int chunk) {
  const int t = (int)(blockIdx.x * blockDim.x + threadIdx.x);
  if (t >= SCAN_CHUNKS) return;
  const int beg = t * chunk;
  const int end = min(beg + chunk, total);
  int s = 0;
  for (int i = beg; i < end; ++i) s += C[i];
  tsum[t] = s;
}

__global__ __launch_bounds__(1024) void gin_scan_b(int* __restrict__ tsum) {
  __shared__ int ls[1024];
  const int t = threadIdx.x;
  int v[8];
  int s = 0;
#pragma unroll
  for (int i = 0; i < 8; ++i) {
    v[i] = tsum[t * 8 + i];
    s += v[i];
  }
  ls[t] = s;
  __syncthreads();
  for (int o = 1; o < 1024; o <<= 1) {
    const int a = (t >= o) ? ls[t - o] : 0;
    __syncthreads();
    ls[t] += a;
    __syncthreads();
  }
  int run = ls[t] - s;
#pragma unroll
  for (int i = 0; i < 8; ++i) {
    tsum[t * 8 + i] = run;
    run += v[i];
  }
}

__global__ __launch_bounds__(256) void gin_scan_c(
    int* __restrict__ C, const int* __restrict__ tsum, int total, int chunk) {
  const int t = (int)(blockIdx.x * blockDim.x + threadIdx.x);
  if (t >= SCAN_CHUNKS) return;
  const int beg = t * chunk;
  const int end = min(beg + chunk, total);
  int run = tsum[t];
  for (int i = beg; i < end; ++i) {
    const int c = C[i];
    C[i] = run;
    run += c;
  }
}

__global__ __launch_bounds__(256) void gin_place_sharded(
    const void* __restrict__ edge_index, int* __restrict__ C,
    int* __restrict__ sorted_src, int n_edges, int n_nodes, int nshard) {
  DETECT_IS64(edge_index);
  const int* ei32 = (const int*)edge_index;
  const long long* ei64 = (const long long*)edge_index;
  int* Cs = C + (size_t)(blockIdx.x & (nshard - 1)) * n_nodes;
  const int i = (int)(blockIdx.x * blockDim.x + threadIdx.x);
  const int stride = (int)(gridDim.x * blockDim.x);
  for (int e = i; e < n_edges; e += stride) {
    int src, dst;
    if (s_is64) {
      src = (int)ei64[e];
      dst = (int)ei64[n_edges + e];
    } else {
      src = ei32[e];
      dst = ei32[n_edges + e];
    }
    const int pos = atomicAdd(&Cs[dst], 1);
    sorted_src[pos] = src;
  }
}

// ---------------------------------------------------------------------------
// Gather-aggregate: ROUND-11 version restored (best measured: 95 us).
// Wave per node, lane = feature, branchless single-edge lockstep over the
// node's S per-shard segments. Round-12/13 lesson: intra-stream pairing and
// quarter-wave variants both regressed (latency- or waste-bound).
// ---------------------------------------------------------------------------
template <int S>
__global__ __launch_bounds__(256) void gin_gather_sharded(
    const float* __restrict__ x, const int* __restrict__ C,
    const int* __restrict__ sorted_src, float* __restrict__ agg,
    int n_nodes) {
  const int lane = threadIdx.x & 63;
  const int wave = (int)((blockIdx.x * blockDim.x + threadIdx.x) >> 6);
  if (wave >= n_nodes) return;

  int p[S], q[S];
  float acc[S];
  bool more = false;
#pragma unroll
  for (int s = 0; s < S; ++s) {
    const int k = s * n_nodes + wave;
    q[s] = C[k];
    p[s] = (k == 0) ? 0 : C[k - 1];
    acc[s] = 0.0f;
    more = more || (p[s] < q[s]);
  }

  while (more) {
    int act[S], srcs[S];
#pragma unroll
    for (int s = 0; s < S; ++s) {
      act[s] = (p[s] < q[s]) ? 1 : 0;
      srcs[s] = sorted_src[act[s] ? p[s] : 0];  // unconditional load
    }
    float rows[S];
#pragma unroll
    for (int s = 0; s < S; ++s) {
      rows[s] = x[(size_t)srcs[s] * D + lane];  // unconditional load
    }
    more = false;
#pragma unroll
    for (int s = 0; s < S; ++s) {
      acc[s] += act[s] ? rows[s] : 0.0f;
      p[s] += act[s];
      more = more || (p[s] < q[s]);
    }
  }

  float r = 0.0f;
#pragma unroll
  for (int s = 0; s < S; ++s) r += acc[s];
  agg[(size_t)wave * D + lane] = r;
}

// ---------------------------------------------------------------------------
// Fallback scatter (if ws too small): scalar float atomics, wave per edge.
// ---------------------------------------------------------------------------
__global__ __launch_bounds__(256) void gin_scatter_atomic(
    const float* __restrict__ x, const void* __restrict__ edge_index,
    float* __restrict__ agg, int n_edges) {
  DETECT_IS64(edge_index);
  const int* ei32 = (const int*)edge_index;
  const long long* ei64 = (const long long*)edge_index;
  const int lane = threadIdx.x & 63;
  int wave = (int)((blockIdx.x * blockDim.x + threadIdx.x) >> 6);
  const int nwaves = (int)((gridDim.x * blockDim.x) >> 6);
  for (int e = wave; e < n_edges; e += nwaves) {
    int src, dst;
    if (s_is64) {
      src = (int)ei64[e];
      dst = (int)ei64[n_edges + e];
    } else {
      src = ei32[e];
      dst = ei32[n_edges + e];
    }
    atomicAdd(&agg[(size_t)dst * D + lane], x[(size_t)src * D + lane]);
  }
}

// ---------------------------------------------------------------------------
// Block-tiled MLP (vector f32 GEMM). Unchanged from round 10/11.
// ---------------------------------------------------------------------------
__global__ __launch_bounds__(256) void gin_mlp_tiled(
    const float* __restrict__ x,
    const float* __restrict__ agg_in,
    const float* __restrict__ eps_p,
    const float* __restrict__ W1, const float* __restrict__ b1,
    const float* __restrict__ W2, const float* __restrict__ b2,
    float* __restrict__ out,
    int n_nodes) {
  __shared__ float zs[128 * 72];   // z tile; reused for h
  __shared__ float w1s[64 * 64];
  __shared__ float w2s[64 * 64];

  const int t = (int)threadIdx.x;
  const int base = (int)blockIdx.x * 128;
  const float scale = 1.0f + eps_p[0];

  {
    const float4* W1v = (const float4*)W1;
    const float4* W2v = (const float4*)W2;
#pragma unroll
    for (int i = 0; i < 4; ++i) {
      const int idx = t + 256 * i;
      const int j = idx >> 4;
      const int kq = idx & 15;
      const int slot = kq ^ ((j >> 2) & 7);
      *(float4*)&w1s[j * 64 + slot * 4] = W1v[idx];
      *(float4*)&w2s[j * 64 + slot * 4] = W2v[idx];
    }
  }

  {
#pragma unroll
    for (int i = 0; i < 8; ++i) {
      const int idx = t + 256 * i;
      const int row = idx >> 4;
      const int kq = idx & 15;
      const int g = base + row;
      float4 zv;
      zv.x = 0.0f; zv.y = 0.0f; zv.z = 0.0f; zv.w = 0.0f;
      if (g < n_nodes) {
        const float4 xv = *(const float4*)(x + (size_t)g * D + kq * 4);
        const float4 av = *(const float4*)(agg_in + (size_t)g * D + kq * 4);
        zv.x = scale * xv.x + av.x;
        zv.y = scale * xv.y + av.y;
        zv.z = scale * xv.z + av.z;
        zv.w = scale * xv.w + av.w;
      }
      *(float4*)&zs[row * 72 + kq * 4] = zv;
    }
  }
  __syncthreads();

  const int jg = t & 15;
  const int mg = t >> 4;
  const float4 b1q = ((const float4*)b1)[jg];
  const float4 b2q = ((const float4*)b2)[jg];
  const int wswz = (jg & 7);

  float acc[8][4];
#pragma unroll
  for (int r = 0; r < 8; ++r) {
    acc[r][0] = b1q.x; acc[r][1] = b1q.y;
    acc[r][2] = b1q.z; acc[r][3] = b1q.w;
  }

#pragma unroll 4
  for (int kq = 0; kq < 16; ++kq) {
    float4 wq[4];
#pragma unroll
    for (int c = 0; c < 4; ++c) {
      wq[c] = *(const float4*)&w1s[(4 * jg + c) * 64 + ((kq ^ wswz) * 4)];
    }
#pragma unroll
    for (int r = 0; r < 8; ++r) {
      const float4 zq = *(const float4*)&zs[(r * 16 + mg) * 72 + kq * 4];
#pragma unroll
      for (int c = 0; c < 4; ++c) {
        acc[r][c] += zq.x * wq[c].x + zq.y * wq[c].y +
                     zq.z * wq[c].z + zq.w * wq[c].w;
      }
    }
  }

  __syncthreads();
#pragma unroll
  for (int r = 0; r < 8; ++r) {
    float4 hv;
    hv.x = fmaxf(acc[r][0], 0.0f);
    hv.y = fmaxf(acc[r][1], 0.0f);
    hv.z = fmaxf(acc[r][2], 0.0f);
    hv.w = fmaxf(acc[r][3], 0.0f);
    *(float4*)&zs[(r * 16 + mg) * 72 + jg * 4] = hv;
  }
  __syncthreads();

#pragma unroll
  for (int r = 0; r < 8; ++r) {
    acc[r][0] = b2q.x; acc[r][1] = b2q.y;
    acc[r][2] = b2q.z; acc[r][3] = b2q.w;
  }
#pragma unroll 4
  for (int kq = 0; kq < 16; ++kq) {
    float4 wq[4];
#pragma unroll
    for (int c = 0; c < 4; ++c) {
      wq[c] = *(const float4*)&w2s[(4 * jg + c) * 64 + ((kq ^ wswz) * 4)];
    }
#pragma unroll
    for (int r = 0; r < 8; ++r) {
      const float4 zq = *(const float4*)&zs[(r * 16 + mg) * 72 + kq * 4];
#pragma unroll
      for (int c = 0; c < 4; ++c) {
        acc[r][c] += zq.x * wq[c].x + zq.y * wq[c].y +
                     zq.z * wq[c].z + zq.w * wq[c].w;
      }
    }
  }

#pragma unroll
  for (int r = 0; r < 8; ++r) {
    const int g = base + r * 16 + mg;
    if (g < n_nodes) {
      float4 ov;
      ov.x = acc[r][0]; ov.y = acc[r][1];
      ov.z = acc[r][2]; ov.w = acc[r][3];
      *(float4*)(out + (size_t)g * D + jg * 4) = ov;
    }
  }
}

extern "C" void kernel_launch(void* const* d_in, const int* in_sizes, int n_in,
                              void* d_out, int out_size, void* d_ws, size_t ws_size,
                              hipStream_t stream) {
  const float* x   = (const float*)d_in[0];
  const void*  ei  = d_in[1];
  const float* eps = (const float*)d_in[2];
  const float* W1  = (const float*)d_in[3];
  const float* b1  = (const float*)d_in[4];
  const float* W2  = (const float*)d_in[5];
  const float* b2  = (const float*)d_in[6];
  float* out = (float*)d_out;

  const int n_nodes = in_sizes[0] / D;
  const int n_edges = in_sizes[1] / 2;

  // ws layout (ints): C[S*n_nodes] | scratch[SCAN_CHUNKS] | sorted[E]
  // (scratch doubles as bt[COOP_BLOCKS] for the fused path.)
  int S = 0;
  for (int cand = 8; cand >= 1; cand >>= 1) {
    const size_t need =
        ((size_t)cand * n_nodes + SCAN_CHUNKS + (size_t)n_edges) * 4;
    if (ws_size >= need) { S = cand; break; }
  }

  if (S > 0) {
    int* C       = (int*)d_ws;
    int* scratch = C + (size_t)S * n_nodes;
    int* sorted  = scratch + SCAN_CHUNKS;
    const int total = S * n_nodes;

    (void)hipMemsetAsync(C, 0, (size_t)total * 4, stream);

    // Cooperative fused path if supported and sizes fit the fixed geometry.
    int dev = 0;
    (void)hipGetDevice(&dev);
    int coop = 0;
    (void)hipDeviceGetAttribute(&coop, hipDeviceAttributeCooperativeLaunch,
                                dev);
    const bool fits =
        (n_edges <= 7 * COOP_NT) && (total <= 4 * COOP_NT);

    if (coop && fits) {
      const void* ei_ = ei;
      int* C_ = C;
      int* bt_ = scratch;
      int* sorted_ = sorted;
      int nE_ = n_edges, nN_ = n_nodes, S_ = S, total_ = total;
      void* args[] = {&ei_, &C_, &bt_, &sorted_, &nE_, &nN_, &S_, &total_};
      (void)hipLaunchCooperativeKernel((void*)gin_fused_sort,
                                       dim3(COOP_BLOCKS), dim3(COOP_THREADS),
                                       args, 0, stream);
    } else {
      gin_hist_sharded<<<EDGE_GRID, EDGE_BLOCK, 0, stream>>>(ei, C, n_edges,
                                                             n_nodes, S);
      const int chunk = (total + SCAN_CHUNKS - 1) / SCAN_CHUNKS;
      gin_scan_a<<<SCAN_CHUNKS / 256, 256, 0, stream>>>(C, scratch, total,
                                                        chunk);
      gin_scan_b<<<1, 1024, 0, stream>>>(scratch);
      gin_scan_c<<<SCAN_CHUNKS / 256, 256, 0, stream>>>(C, scratch, total,
                                                        chunk);
      gin_place_sharded<<<EDGE_GRID, EDGE_BLOCK, 0, stream>>>(ei, C, sorted,
                                                              n_edges,
                                                              n_nodes, S);
    }

    const int gather_blocks = (n_nodes * 64 + 255) / 256;
    switch (S) {
      case 8:
        gin_gather_sharded<8><<<gather_blocks, 256, 0, stream>>>(
            x, C, sorted, out, n_nodes);
        break;
      case 4:
        gin_gather_sharded<4><<<gather_blocks, 256, 0, stream>>>(
            x, C, sorted, out, n_nodes);
        break;
      case 2:
        gin_gather_sharded<2><<<gather_blocks, 256, 0, stream>>>(
            x, C, sorted, out, n_nodes);
        break;
      default:
        gin_gather_sharded<1><<<gather_blocks, 256, 0, stream>>>(
            x, C, sorted, out, n_nodes);
        break;
    }
  } else {
    (void)hipMemsetAsync(out, 0, (size_t)n_nodes * D * sizeof(float), stream);
    gin_scatter_atomic<<<4096, 256, 0, stream>>>(x, ei, out, n_edges);
  }

  const int mlp_blocks = (n_nodes + 127) / 128;
  gin_mlp_tiled<<<mlp_blocks, 256, 0, stream>>>(x, out, eps, W1, b1, W2, b2,
                                                out, n_nodes);
}

// Round 15
// 354.335 us; speedup vs baseline: 1.9316x; 1.9316x over previous
//
#include <hip/hip_runtime.h>

#define D 64
#define CHUNK 64      // sorted entries per wave in the flat gather
#define NGROUP 8      // XCD range groups for hist/place

// ---------------------------------------------------------------------------
// edge_index dtype detection (int32 vs int64), done per-block on device.
// int64 little-endian with values < 2^32 => every odd uint32 word is 0.
// ---------------------------------------------------------------------------
#define DETECT_IS64(ei)                                        \
  __shared__ int s_is64;                                       \
  if (threadIdx.x == 0) {                                      \
    const unsigned int* w_ = (const unsigned int*)(ei);        \
    int is64_ = 1;                                             \
    for (int i_ = 0; i_ < 64; ++i_) {                          \
      if (w_[2 * i_ + 1] != 0u) { is64_ = 0; break; }          \
    }                                                          \
    s_is64 = is64_;                                            \
  }                                                            \
  __syncthreads();

#define EDGE_GRID 4096
#define EDGE_BLOCK 256
#define SCAN_CHUNKS 8192

// ---------------------------------------------------------------------------
// Kernel 1: RANGE-FILTERED histogram (node-major C, XCD-local atomics).
// Blocks with (b & 7) == r own node range r; the 512 blocks of a group
// jointly grid-stride ALL edges and count only dsts in their range.
// C[dst] lines for range r are touched only by XCD r (b%8 -> XCD r).
// Round-14 lesson (coop fusion, 535us): keep scatter phases at full grid.
// Round-4 lesson (unsharded place, 135us): never let cursor lines migrate.
// ---------------------------------------------------------------------------
__global__ __launch_bounds__(256) void gin_hist_ranged(
    const void* __restrict__ edge_index, int* __restrict__ C,
    int n_edges, int n_nodes) {
  DETECT_IS64(edge_index);
  const int* ei32 = (const int*)edge_index;
  const long long* ei64 = (const long long*)edge_index;
  const int r = (int)(blockIdx.x & (NGROUP - 1));
  const int nlo = (int)(((long long)n_nodes * r) / NGROUP);
  const int nhi = (int)(((long long)n_nodes * (r + 1)) / NGROUP);
  const int i = (int)((blockIdx.x >> 3) * blockDim.x + threadIdx.x);
  const int stride = (int)((gridDim.x >> 3) * blockDim.x);
  for (int e = i; e < n_edges; e += stride) {
    const int dst = s_is64 ? (int)ei64[n_edges + e] : ei32[n_edges + e];
    if (dst >= nlo && dst < nhi) atomicAdd(&C[dst], 1);
  }
}

// ---------------------------------------------------------------------------
// Kernels 2a/2b/2c: in-place exclusive scan of C[total], SCAN_CHUNKS chunks.
// ---------------------------------------------------------------------------
__global__ __launch_bounds__(256) void gin_scan_a(
    const int* __restrict__ C, int* __restrict__ tsum, int total, int chunk) {
  const int t = (int)(blockIdx.x * blockDim.x + threadIdx.x);
  if (t >= SCAN_CHUNKS) return;
  const int beg = t * chunk;
  const int end = min(beg + chunk, total);
  int s = 0;
  for (int i = beg; i < end; ++i) s += C[i];
  tsum[t] = s;
}

__global__ __launch_bounds__(1024) void gin_scan_b(int* __restrict__ tsum) {
  __shared__ int ls[1024];
  const int t = threadIdx.x;
  int v[8];
  int s = 0;
#pragma unroll
  for (int i = 0; i < 8; ++i) {
    v[i] = tsum[t * 8 + i];
    s += v[i];
  }
  ls[t] = s;
  __syncthreads();
  for (int o = 1; o < 1024; o <<= 1) {
    const int a = (t >= o) ? ls[t - o] : 0;
    __syncthreads();
    ls[t] += a;
    __syncthreads();
  }
  int run = ls[t] - s;
#pragma unroll
  for (int i = 0; i < 8; ++i) {
    tsum[t * 8 + i] = run;
    run += v[i];
  }
}

__global__ __launch_bounds__(256) void gin_scan_c(
    int* __restrict__ C, const int* __restrict__ tsum, int total, int chunk) {
  const int t = (int)(blockIdx.x * blockDim.x + threadIdx.x);
  if (t >= SCAN_CHUNKS) return;
  const int beg = t * chunk;
  const int end = min(beg + chunk, total);
  int run = tsum[t];
  for (int i = beg; i < end; ++i) {
    const int c = C[i];
    C[i] = run;
    run += c;
  }
}

// ---------------------------------------------------------------------------
// Kernel 3: RANGE-FILTERED placement (node-major sorted order).
// Same geometry as hist_ranged. pos = atomicAdd(&C[dst],1): cursor lines and
// the contiguous sorted-region for range r stay XCD-local -> L2 write-merge.
// After this kernel, C[k] = prefix[k+1] (segment END of node k).
// ---------------------------------------------------------------------------
__global__ __launch_bounds__(256) void gin_place_ranged(
    const void* __restrict__ edge_index, int* __restrict__ C,
    int* __restrict__ sorted_src, int n_edges, int n_nodes) {
  DETECT_IS64(edge_index);
  const int* ei32 = (const int*)edge_index;
  const long long* ei64 = (const long long*)edge_index;
  const int r = (int)(blockIdx.x & (NGROUP - 1));
  const int nlo = (int)(((long long)n_nodes * r) / NGROUP);
  const int nhi = (int)(((long long)n_nodes * (r + 1)) / NGROUP);
  const int i = (int)((blockIdx.x >> 3) * blockDim.x + threadIdx.x);
  const int stride = (int)((gridDim.x >> 3) * blockDim.x);
  for (int e = i; e < n_edges; e += stride) {
    const int dst = s_is64 ? (int)ei64[n_edges + e] : ei32[n_edges + e];
    if (dst >= nlo && dst < nhi) {
      const int src = s_is64 ? (int)ei64[e] : ei32[e];
      const int pos = atomicAdd(&C[dst], 1);
      sorted_src[pos] = src;
    }
  }
}

// ---------------------------------------------------------------------------
// Kernel 4: FLAT segmented-sum gather. One wave per CHUNK=64 consecutive
// sorted entries; lane = feature. Zero wasted iterations (round-11 lockstep
// burned ~56 VALU-instr/edge at 2.5x waste). 64 srcs staged (uniform ->
// scalar loads), 64 independent row loads in flight, then a sequential
// run-accumulate with segment boundaries from C (node-major).
// Interior runs (segment fully inside chunk) plain-store; boundary runs
// atomicAdd (agg pre-zeroed; degree-0 nodes stay zero from memset).
// ---------------------------------------------------------------------------
__global__ __launch_bounds__(256) void gin_gather_flat(
    const float* __restrict__ x, const int* __restrict__ C,
    const int* __restrict__ sorted_src, float* __restrict__ agg,
    int n_nodes, int n_edges) {
  const int lane = (int)(threadIdx.x & 63);
  const int wave = (int)((blockIdx.x * blockDim.x + threadIdx.x) >> 6);
  const int start = wave * CHUNK;
  if (start >= n_edges) return;
  const int cend = min(start + CHUNK, n_edges);

  // binary search: first k with C[k] > start (C[k] = segment end of node k)
  int lo = 0, hi = n_nodes - 1;
  while (lo < hi) {
    const int mid = (lo + hi) >> 1;
    if (C[mid] > start) hi = mid; else lo = mid + 1;
  }
  int k = lo;
  int end = C[k];
  int segbeg = (k == 0) ? 0 : C[k - 1];

  // stage sources (uniform addresses -> scalar loads)
  int srcs[CHUNK];
#pragma unroll
  for (int i = 0; i < CHUNK; ++i) {
    srcs[i] = sorted_src[min(start + i, n_edges - 1)];
  }
  // stage rows: 64 independent coalesced 256B row-reads in flight
  float rows[CHUNK];
#pragma unroll
  for (int i = 0; i < CHUNK; ++i) {
    rows[i] = x[(size_t)srcs[i] * D + lane];
  }

  float acc = 0.0f;
  int runstart = start;
#pragma unroll
  for (int i = 0; i < CHUNK; ++i) {
    const int pos = start + i;
    if (pos >= cend) break;  // tail chunk only
    acc += rows[i];
    if (pos + 1 == end) {
      // segment k complete at pos+1
      const size_t off = (size_t)k * D + lane;
      if (segbeg >= start) {
        agg[off] = acc;               // interior: sole writer
      } else {
        atomicAdd(&agg[off], acc);    // crosses chunk start
      }
      acc = 0.0f;
      runstart = pos + 1;
      if (pos + 1 < cend) {
        segbeg = end;
        ++k;
        end = C[k];
        while (end == segbeg) { ++k; end = C[k]; }  // skip empty nodes
      }
    }
  }
  // trailing open run: segment continues into the next chunk
  if (runstart < cend) {
    atomicAdd(&agg[(size_t)k * D + lane], acc);
  }
}

// ---------------------------------------------------------------------------
// Fallback scatter (if ws too small): scalar float atomics, wave per edge.
// ---------------------------------------------------------------------------
__global__ __launch_bounds__(256) void gin_scatter_atomic(
    const float* __restrict__ x, const void* __restrict__ edge_index,
    float* __restrict__ agg, int n_edges) {
  DETECT_IS64(edge_index);
  const int* ei32 = (const int*)edge_index;
  const long long* ei64 = (const long long*)edge_index;
  const int lane = threadIdx.x & 63;
  int wave = (int)((blockIdx.x * blockDim.x + threadIdx.x) >> 6);
  const int nwaves = (int)((gridDim.x * blockDim.x) >> 6);
  for (int e = wave; e < n_edges; e += nwaves) {
    int src, dst;
    if (s_is64) {
      src = (int)ei64[e];
      dst = (int)ei64[n_edges + e];
    } else {
      src = ei32[e];
      dst = ei32[n_edges + e];
    }
    atomicAdd(&agg[(size_t)dst * D + lane], x[(size_t)src * D + lane]);
  }
}

// ---------------------------------------------------------------------------
// Kernel 5: block-tiled MLP (vector f32 GEMM). Unchanged from round 10/11.
// ---------------------------------------------------------------------------
__global__ __launch_bounds__(256) void gin_mlp_tiled(
    const float* __restrict__ x,
    const float* __restrict__ agg_in,
    const float* __restrict__ eps_p,
    const float* __restrict__ W1, const float* __restrict__ b1,
    const float* __restrict__ W2, const float* __restrict__ b2,
    float* __restrict__ out,
    int n_nodes) {
  __shared__ float zs[128 * 72];   // z tile; reused for h
  __shared__ float w1s[64 * 64];
  __shared__ float w2s[64 * 64];

  const int t = (int)threadIdx.x;
  const int base = (int)blockIdx.x * 128;
  const float scale = 1.0f + eps_p[0];

  {
    const float4* W1v = (const float4*)W1;
    const float4* W2v = (const float4*)W2;
#pragma unroll
    for (int i = 0; i < 4; ++i) {
      const int idx = t + 256 * i;
      const int j = idx >> 4;
      const int kq = idx & 15;
      const int slot = kq ^ ((j >> 2) & 7);
      *(float4*)&w1s[j * 64 + slot * 4] = W1v[idx];
      *(float4*)&w2s[j * 64 + slot * 4] = W2v[idx];
    }
  }

  {
#pragma unroll
    for (int i = 0; i < 8; ++i) {
      const int idx = t + 256 * i;
      const int row = idx >> 4;
      const int kq = idx & 15;
      const int g = base + row;
      float4 zv;
      zv.x = 0.0f; zv.y = 0.0f; zv.z = 0.0f; zv.w = 0.0f;
      if (g < n_nodes) {
        const float4 xv = *(const float4*)(x + (size_t)g * D + kq * 4);
        const float4 av = *(const float4*)(agg_in + (size_t)g * D + kq * 4);
        zv.x = scale * xv.x + av.x;
        zv.y = scale * xv.y + av.y;
        zv.z = scale * xv.z + av.z;
        zv.w = scale * xv.w + av.w;
      }
      *(float4*)&zs[row * 72 + kq * 4] = zv;
    }
  }
  __syncthreads();

  const int jg = t & 15;
  const int mg = t >> 4;
  const float4 b1q = ((const float4*)b1)[jg];
  const float4 b2q = ((const float4*)b2)[jg];
  const int wswz = (jg & 7);

  float acc[8][4];
#pragma unroll
  for (int r = 0; r < 8; ++r) {
    acc[r][0] = b1q.x; acc[r][1] = b1q.y;
    acc[r][2] = b1q.z; acc[r][3] = b1q.w;
  }

#pragma unroll 4
  for (int kq = 0; kq < 16; ++kq) {
    float4 wq[4];
#pragma unroll
    for (int c = 0; c < 4; ++c) {
      wq[c] = *(const float4*)&w1s[(4 * jg + c) * 64 + ((kq ^ wswz) * 4)];
    }
#pragma unroll
    for (int r = 0; r < 8; ++r) {
      const float4 zq = *(const float4*)&zs[(r * 16 + mg) * 72 + kq * 4];
#pragma unroll
      for (int c = 0; c < 4; ++c) {
        acc[r][c] += zq.x * wq[c].x + zq.y * wq[c].y +
                     zq.z * wq[c].z + zq.w * wq[c].w;
      }
    }
  }

  __syncthreads();
#pragma unroll
  for (int r = 0; r < 8; ++r) {
    float4 hv;
    hv.x = fmaxf(acc[r][0], 0.0f);
    hv.y = fmaxf(acc[r][1], 0.0f);
    hv.z = fmaxf(acc[r][2], 0.0f);
    hv.w = fmaxf(acc[r][3], 0.0f);
    *(float4*)&zs[(r * 16 + mg) * 72 + jg * 4] = hv;
  }
  __syncthreads();

#pragma unroll
  for (int r = 0; r < 8; ++r) {
    acc[r][0] = b2q.x; acc[r][1] = b2q.y;
    acc[r][2] = b2q.z; acc[r][3] = b2q.w;
  }
#pragma unroll 4
  for (int kq = 0; kq < 16; ++kq) {
    float4 wq[4];
#pragma unroll
    for (int c = 0; c < 4; ++c) {
      wq[c] = *(const float4*)&w2s[(4 * jg + c) * 64 + ((kq ^ wswz) * 4)];
    }
#pragma unroll
    for (int r = 0; r < 8; ++r) {
      const float4 zq = *(const float4*)&zs[(r * 16 + mg) * 72 + kq * 4];
#pragma unroll
      for (int c = 0; c < 4; ++c) {
        acc[r][c] += zq.x * wq[c].x + zq.y * wq[c].y +
                     zq.z * wq[c].z + zq.w * wq[c].w;
      }
    }
  }

#pragma unroll
  for (int r = 0; r < 8; ++r) {
    const int g = base + r * 16 + mg;
    if (g < n_nodes) {
      float4 ov;
      ov.x = acc[r][0]; ov.y = acc[r][1];
      ov.z = acc[r][2]; ov.w = acc[r][3];
      *(float4*)(out + (size_t)g * D + jg * 4) = ov;
    }
  }
}

extern "C" void kernel_launch(void* const* d_in, const int* in_sizes, int n_in,
                              void* d_out, int out_size, void* d_ws, size_t ws_size,
                              hipStream_t stream) {
  const float* x   = (const float*)d_in[0];
  const void*  ei  = d_in[1];
  const float* eps = (const float*)d_in[2];
  const float* W1  = (const float*)d_in[3];
  const float* b1  = (const float*)d_in[4];
  const float* W2  = (const float*)d_in[5];
  const float* b2  = (const float*)d_in[6];
  float* out = (float*)d_out;

  const int n_nodes = in_sizes[0] / D;
  const int n_edges = in_sizes[1] / 2;

  // ws layout (ints): C[n_nodes] | tsum[SCAN_CHUNKS] | sorted[n_edges]
  const size_t need = ((size_t)n_nodes + SCAN_CHUNKS + (size_t)n_edges) * 4;

  if (ws_size >= need) {
    int* C      = (int*)d_ws;
    int* tsum   = C + n_nodes;
    int* sorted = tsum + SCAN_CHUNKS;

    (void)hipMemsetAsync(C, 0, (size_t)n_nodes * 4, stream);
    // agg (= out) must be pre-zeroed: flat gather atomic-flushes boundary
    // runs and leaves degree-0 rows untouched.
    (void)hipMemsetAsync(out, 0, (size_t)n_nodes * D * sizeof(float), stream);

    gin_hist_ranged<<<EDGE_GRID, EDGE_BLOCK, 0, stream>>>(ei, C, n_edges,
                                                          n_nodes);

    const int chunk = (n_nodes + SCAN_CHUNKS - 1) / SCAN_CHUNKS;
    gin_scan_a<<<SCAN_CHUNKS / 256, 256, 0, stream>>>(C, tsum, n_nodes,
                                                      chunk);
    gin_scan_b<<<1, 1024, 0, stream>>>(tsum);
    gin_scan_c<<<SCAN_CHUNKS / 256, 256, 0, stream>>>(C, tsum, n_nodes,
                                                      chunk);

    gin_place_ranged<<<EDGE_GRID, EDGE_BLOCK, 0, stream>>>(ei, C, sorted,
                                                           n_edges, n_nodes);

    const int nchunks = (n_edges + CHUNK - 1) / CHUNK;
    const int gather_blocks = (nchunks + 3) / 4;  // 4 waves per block
    gin_gather_flat<<<gather_blocks, 256, 0, stream>>>(x, C, sorted, out,
                                                       n_nodes, n_edges);
  } else {
    (void)hipMemsetAsync(out, 0, (size_t)n_nodes * D * sizeof(float), stream);
    gin_scatter_atomic<<<4096, 256, 0, stream>>>(x, ei, out, n_edges);
  }

  const int mlp_blocks = (n_nodes + 127) / 128;
  gin_mlp_tiled<<<mlp_blocks, 256, 0, stream>>>(x, out, eps, W1, b1, W2, b2,
                                                out, n_nodes);
}

// Round 16
// 312.695 us; speedup vs baseline: 2.1888x; 1.1332x over previous
//
#include <hip/hip_runtime.h>

#define D 64
#define CHUNK 32      // sorted entries per wave in the flat gather (r15: 64 -> VGPR cliff)
#define NGROUP 8      // XCD range groups for hist/place

// ---------------------------------------------------------------------------
// edge_index dtype detection (int32 vs int64), done per-block on device.
// ---------------------------------------------------------------------------
#define DETECT_IS64(ei)                                        \
  __shared__ int s_is64;                                       \
  if (threadIdx.x == 0) {                                      \
    const unsigned int* w_ = (const unsigned int*)(ei);        \
    int is64_ = 1;                                             \
    for (int i_ = 0; i_ < 64; ++i_) {                          \
      if (w_[2 * i_ + 1] != 0u) { is64_ = 0; break; }          \
    }                                                          \
    s_is64 = is64_;                                            \
  }                                                            \
  __syncthreads();

#define EDGE_GRID 4096
#define EDGE_BLOCK 256
#define SCAN_CHUNKS 8192

// ---------------------------------------------------------------------------
// Kernel 1: RANGE-FILTERED histogram (node-major C, XCD-local atomics).
// Blocks with (b & 7) == r own node range r; the 512 blocks of a group
// jointly grid-stride ALL edges and count only dsts in their range.
// ---------------------------------------------------------------------------
__global__ __launch_bounds__(256) void gin_hist_ranged(
    const void* __restrict__ edge_index, int* __restrict__ C,
    int n_edges, int n_nodes) {
  DETECT_IS64(edge_index);
  const int* ei32 = (const int*)edge_index;
  const long long* ei64 = (const long long*)edge_index;
  const int r = (int)(blockIdx.x & (NGROUP - 1));
  const int nlo = (int)(((long long)n_nodes * r) / NGROUP);
  const int nhi = (int)(((long long)n_nodes * (r + 1)) / NGROUP);
  const int i = (int)((blockIdx.x >> 3) * blockDim.x + threadIdx.x);
  const int stride = (int)((gridDim.x >> 3) * blockDim.x);
  for (int e = i; e < n_edges; e += stride) {
    const int dst = s_is64 ? (int)ei64[n_edges + e] : ei32[n_edges + e];
    if (dst >= nlo && dst < nhi) atomicAdd(&C[dst], 1);
  }
}

// ---------------------------------------------------------------------------
// Kernels 2a/2b/2c: in-place exclusive scan of C[total], SCAN_CHUNKS chunks.
// ---------------------------------------------------------------------------
__global__ __launch_bounds__(256) void gin_scan_a(
    const int* __restrict__ C, int* __restrict__ tsum, int total, int chunk) {
  const int t = (int)(blockIdx.x * blockDim.x + threadIdx.x);
  if (t >= SCAN_CHUNKS) return;
  const int beg = t * chunk;
  const int end = min(beg + chunk, total);
  int s = 0;
  for (int i = beg; i < end; ++i) s += C[i];
  tsum[t] = s;
}

__global__ __launch_bounds__(1024) void gin_scan_b(int* __restrict__ tsum) {
  __shared__ int ls[1024];
  const int t = threadIdx.x;
  int v[8];
  int s = 0;
#pragma unroll
  for (int i = 0; i < 8; ++i) {
    v[i] = tsum[t * 8 + i];
    s += v[i];
  }
  ls[t] = s;
  __syncthreads();
  for (int o = 1; o < 1024; o <<= 1) {
    const int a = (t >= o) ? ls[t - o] : 0;
    __syncthreads();
    ls[t] += a;
    __syncthreads();
  }
  int run = ls[t] - s;
#pragma unroll
  for (int i = 0; i < 8; ++i) {
    tsum[t * 8 + i] = run;
    run += v[i];
  }
}

__global__ __launch_bounds__(256) void gin_scan_c(
    int* __restrict__ C, const int* __restrict__ tsum, int total, int chunk) {
  const int t = (int)(blockIdx.x * blockDim.x + threadIdx.x);
  if (t >= SCAN_CHUNKS) return;
  const int beg = t * chunk;
  const int end = min(beg + chunk, total);
  int run = tsum[t];
  for (int i = beg; i < end; ++i) {
    const int c = C[i];
    C[i] = run;
    run += c;
  }
}

// ---------------------------------------------------------------------------
// Kernel 3: RANGE-FILTERED placement (node-major sorted order).
// After this kernel, C[k] = prefix[k+1] (segment END of node k).
// ---------------------------------------------------------------------------
__global__ __launch_bounds__(256) void gin_place_ranged(
    const void* __restrict__ edge_index, int* __restrict__ C,
    int* __restrict__ sorted_src, int n_edges, int n_nodes) {
  DETECT_IS64(edge_index);
  const int* ei32 = (const int*)edge_index;
  const long long* ei64 = (const long long*)edge_index;
  const int r = (int)(blockIdx.x & (NGROUP - 1));
  const int nlo = (int)(((long long)n_nodes * r) / NGROUP);
  const int nhi = (int)(((long long)n_nodes * (r + 1)) / NGROUP);
  const int i = (int)((blockIdx.x >> 3) * blockDim.x + threadIdx.x);
  const int stride = (int)((gridDim.x >> 3) * blockDim.x);
  for (int e = i; e < n_edges; e += stride) {
    const int dst = s_is64 ? (int)ei64[n_edges + e] : ei32[n_edges + e];
    if (dst >= nlo && dst < nhi) {
      const int src = s_is64 ? (int)ei64[e] : ei32[e];
      const int pos = atomicAdd(&C[dst], 1);
      sorted_src[pos] = src;
    }
  }
}

// ---------------------------------------------------------------------------
// Kernel 4: FLAT segmented-sum gather, CHUNK=32.
// r15 lesson: CHUNK=64 staged 128 regs -> VGPR 120, occupancy 20.7%,
// latency-bound at 148us. Fixes: (a) CHUNK 32 halves row staging;
// (b) srcs forced into SGPRs via readfirstlane (they are wave-uniform but
// divergence analysis can't prove tid>>6 uniform -> they burned VGPRs).
// ---------------------------------------------------------------------------
__global__ __launch_bounds__(256) void gin_gather_flat(
    const float* __restrict__ x, const int* __restrict__ C,
    const int* __restrict__ sorted_src, float* __restrict__ agg,
    int n_nodes, int n_edges) {
  const int lane = (int)(threadIdx.x & 63);
  const int wave = (int)((blockIdx.x * blockDim.x + threadIdx.x) >> 6);
  const int start = wave * CHUNK;
  if (start >= n_edges) return;
  const int cend = min(start + CHUNK, n_edges);

  // binary search: first k with C[k] > start (C[k] = segment end of node k)
  int lo = 0, hi = n_nodes - 1;
  while (lo < hi) {
    const int mid = (lo + hi) >> 1;
    if (C[mid] > start) hi = mid; else lo = mid + 1;
  }
  int k = lo;
  int end = C[k];
  int segbeg = (k == 0) ? 0 : C[k - 1];

  // stage sources into SGPRs (wave-uniform values)
  int srcs[CHUNK];
#pragma unroll
  for (int i = 0; i < CHUNK; ++i) {
    srcs[i] = __builtin_amdgcn_readfirstlane(
        sorted_src[min(start + i, n_edges - 1)]);
  }
  // stage rows: CHUNK independent coalesced 256B row-reads in flight
  float rows[CHUNK];
#pragma unroll
  for (int i = 0; i < CHUNK; ++i) {
    rows[i] = x[(size_t)srcs[i] * D + lane];
  }

  float acc = 0.0f;
  int runstart = start;
#pragma unroll
  for (int i = 0; i < CHUNK; ++i) {
    const int pos = start + i;
    if (pos >= cend) break;  // tail chunk only
    acc += rows[i];
    if (pos + 1 == end) {
      // segment k complete at pos+1
      const size_t off = (size_t)k * D + lane;
      if (segbeg >= start) {
        agg[off] = acc;               // interior: sole writer
      } else {
        atomicAdd(&agg[off], acc);    // crosses chunk start
      }
      acc = 0.0f;
      runstart = pos + 1;
      if (pos + 1 < cend) {
        segbeg = end;
        ++k;
        end = C[k];
        while (end == segbeg) { ++k; end = C[k]; }  // skip empty nodes
      }
    }
  }
  // trailing open run: segment continues into the next chunk
  if (runstart < cend) {
    atomicAdd(&agg[(size_t)k * D + lane], acc);
  }
}

// ---------------------------------------------------------------------------
// Fallback scatter (if ws too small): scalar float atomics, wave per edge.
// ---------------------------------------------------------------------------
__global__ __launch_bounds__(256) void gin_scatter_atomic(
    const float* __restrict__ x, const void* __restrict__ edge_index,
    float* __restrict__ agg, int n_edges) {
  DETECT_IS64(edge_index);
  const int* ei32 = (const int*)edge_index;
  const long long* ei64 = (const long long*)edge_index;
  const int lane = threadIdx.x & 63;
  int wave = (int)((blockIdx.x * blockDim.x + threadIdx.x) >> 6);
  const int nwaves = (int)((gridDim.x * blockDim.x) >> 6);
  for (int e = wave; e < n_edges; e += nwaves) {
    int src, dst;
    if (s_is64) {
      src = (int)ei64[e];
      dst = (int)ei64[n_edges + e];
    } else {
      src = ei32[e];
      dst = ei32[n_edges + e];
    }
    atomicAdd(&agg[(size_t)dst * D + lane], x[(size_t)src * D + lane]);
  }
}

// ---------------------------------------------------------------------------
// Kernel 5: block-tiled MLP (vector f32 GEMM). Unchanged from round 10/11.
// ---------------------------------------------------------------------------
__global__ __launch_bounds__(256) void gin_mlp_tiled(
    const float* __restrict__ x,
    const float* __restrict__ agg_in,
    const float* __restrict__ eps_p,
    const float* __restrict__ W1, const float* __restrict__ b1,
    const float* __restrict__ W2, const float* __restrict__ b2,
    float* __restrict__ out,
    int n_nodes) {
  __shared__ float zs[128 * 72];   // z tile; reused for h
  __shared__ float w1s[64 * 64];
  __shared__ float w2s[64 * 64];

  const int t = (int)threadIdx.x;
  const int base = (int)blockIdx.x * 128;
  const float scale = 1.0f + eps_p[0];

  {
    const float4* W1v = (const float4*)W1;
    const float4* W2v = (const float4*)W2;
#pragma unroll
    for (int i = 0; i < 4; ++i) {
      const int idx = t + 256 * i;
      const int j = idx >> 4;
      const int kq = idx & 15;
      const int slot = kq ^ ((j >> 2) & 7);
      *(float4*)&w1s[j * 64 + slot * 4] = W1v[idx];
      *(float4*)&w2s[j * 64 + slot * 4] = W2v[idx];
    }
  }

  {
#pragma unroll
    for (int i = 0; i < 8; ++i) {
      const int idx = t + 256 * i;
      const int row = idx >> 4;
      const int kq = idx & 15;
      const int g = base + row;
      float4 zv;
      zv.x = 0.0f; zv.y = 0.0f; zv.z = 0.0f; zv.w = 0.0f;
      if (g < n_nodes) {
        const float4 xv = *(const float4*)(x + (size_t)g * D + kq * 4);
        const float4 av = *(const float4*)(agg_in + (size_t)g * D + kq * 4);
        zv.x = scale * xv.x + av.x;
        zv.y = scale * xv.y + av.y;
        zv.z = scale * xv.z + av.z;
        zv.w = scale * xv.w + av.w;
      }
      *(float4*)&zs[row * 72 + kq * 4] = zv;
    }
  }
  __syncthreads();

  const int jg = t & 15;
  const int mg = t >> 4;
  const float4 b1q = ((const float4*)b1)[jg];
  const float4 b2q = ((const float4*)b2)[jg];
  const int wswz = (jg & 7);

  float acc[8][4];
#pragma unroll
  for (int r = 0; r < 8; ++r) {
    acc[r][0] = b1q.x; acc[r][1] = b1q.y;
    acc[r][2] = b1q.z; acc[r][3] = b1q.w;
  }

#pragma unroll 4
  for (int kq = 0; kq < 16; ++kq) {
    float4 wq[4];
#pragma unroll
    for (int c = 0; c < 4; ++c) {
      wq[c] = *(const float4*)&w1s[(4 * jg + c) * 64 + ((kq ^ wswz) * 4)];
    }
#pragma unroll
    for (int r = 0; r < 8; ++r) {
      const float4 zq = *(const float4*)&zs[(r * 16 + mg) * 72 + kq * 4];
#pragma unroll
      for (int c = 0; c < 4; ++c) {
        acc[r][c] += zq.x * wq[c].x + zq.y * wq[c].y +
                     zq.z * wq[c].z + zq.w * wq[c].w;
      }
    }
  }

  __syncthreads();
#pragma unroll
  for (int r = 0; r < 8; ++r) {
    float4 hv;
    hv.x = fmaxf(acc[r][0], 0.0f);
    hv.y = fmaxf(acc[r][1], 0.0f);
    hv.z = fmaxf(acc[r][2], 0.0f);
    hv.w = fmaxf(acc[r][3], 0.0f);
    *(float4*)&zs[(r * 16 + mg) * 72 + jg * 4] = hv;
  }
  __syncthreads();

#pragma unroll
  for (int r = 0; r < 8; ++r) {
    acc[r][0] = b2q.x; acc[r][1] = b2q.y;
    acc[r][2] = b2q.z; acc[r][3] = b2q.w;
  }
#pragma unroll 4
  for (int kq = 0; kq < 16; ++kq) {
    float4 wq[4];
#pragma unroll
    for (int c = 0; c < 4; ++c) {
      wq[c] = *(const float4*)&w2s[(4 * jg + c) * 64 + ((kq ^ wswz) * 4)];
    }
#pragma unroll
    for (int r = 0; r < 8; ++r) {
      const float4 zq = *(const float4*)&zs[(r * 16 + mg) * 72 + kq * 4];
#pragma unroll
      for (int c = 0; c < 4; ++c) {
        acc[r][c] += zq.x * wq[c].x + zq.y * wq[c].y +
                     zq.z * wq[c].z + zq.w * wq[c].w;
      }
    }
  }

#pragma unroll
  for (int r = 0; r < 8; ++r) {
    const int g = base + r * 16 + mg;
    if (g < n_nodes) {
      float4 ov;
      ov.x = acc[r][0]; ov.y = acc[r][1];
      ov.z = acc[r][2]; ov.w = acc[r][3];
      *(float4*)(out + (size_t)g * D + jg * 4) = ov;
    }
  }
}

extern "C" void kernel_launch(void* const* d_in, const int* in_sizes, int n_in,
                              void* d_out, int out_size, void* d_ws, size_t ws_size,
                              hipStream_t stream) {
  const float* x   = (const float*)d_in[0];
  const void*  ei  = d_in[1];
  const float* eps = (const float*)d_in[2];
  const float* W1  = (const float*)d_in[3];
  const float* b1  = (const float*)d_in[4];
  const float* W2  = (const float*)d_in[5];
  const float* b2  = (const float*)d_in[6];
  float* out = (float*)d_out;

  const int n_nodes = in_sizes[0] / D;
  const int n_edges = in_sizes[1] / 2;

  // ws layout (ints): C[n_nodes] | tsum[SCAN_CHUNKS] | sorted[n_edges]
  const size_t need = ((size_t)n_nodes + SCAN_CHUNKS + (size_t)n_edges) * 4;

  if (ws_size >= need) {
    int* C      = (int*)d_ws;
    int* tsum   = C + n_nodes;
    int* sorted = tsum + SCAN_CHUNKS;

    (void)hipMemsetAsync(C, 0, (size_t)n_nodes * 4, stream);
    // agg (= out) must be pre-zeroed: flat gather atomic-flushes boundary
    // runs and leaves degree-0 rows untouched.
    (void)hipMemsetAsync(out, 0, (size_t)n_nodes * D * sizeof(float), stream);

    gin_hist_ranged<<<EDGE_GRID, EDGE_BLOCK, 0, stream>>>(ei, C, n_edges,
                                                          n_nodes);

    const int chunk = (n_nodes + SCAN_CHUNKS - 1) / SCAN_CHUNKS;
    gin_scan_a<<<SCAN_CHUNKS / 256, 256, 0, stream>>>(C, tsum, n_nodes,
                                                      chunk);
    gin_scan_b<<<1, 1024, 0, stream>>>(tsum);
    gin_scan_c<<<SCAN_CHUNKS / 256, 256, 0, stream>>>(C, tsum, n_nodes,
                                                      chunk);

    gin_place_ranged<<<EDGE_GRID, EDGE_BLOCK, 0, stream>>>(ei, C, sorted,
                                                           n_edges, n_nodes);

    const int nchunks = (n_edges + CHUNK - 1) / CHUNK;
    const int gather_blocks = (nchunks + 3) / 4;  // 4 waves per block
    gin_gather_flat<<<gather_blocks, 256, 0, stream>>>(x, C, sorted, out,
                                                       n_nodes, n_edges);
  } else {
    (void)hipMemsetAsync(out, 0, (size_t)n_nodes * D * sizeof(float), stream);
    gin_scatter_atomic<<<4096, 256, 0, stream>>>(x, ei, out, n_edges);
  }

  const int mlp_blocks = (n_nodes + 127) / 128;
  gin_mlp_tiled<<<mlp_blocks, 256, 0, stream>>>(x, out, eps, W1, b1, W2, b2,
                                                out, n_nodes);
}

// Round 17
// 284.402 us; speedup vs baseline: 2.4065x; 1.0995x over previous
//
#include <hip/hip_runtime.h>

#define D 64
#define CHUNK 32      // sorted entries per wave in the flat gather
#define NGROUP 8      // XCD range groups for hist/place

// ---------------------------------------------------------------------------
// edge_index dtype detection (int32 vs int64), done per-block on device.
// Only used by gin_convert and the fallback kernels.
// ---------------------------------------------------------------------------
#define DETECT_IS64(ei)                                        \
  __shared__ int s_is64;                                       \
  if (threadIdx.x == 0) {                                      \
    const unsigned int* w_ = (const unsigned int*)(ei);        \
    int is64_ = 1;                                             \
    for (int i_ = 0; i_ < 64; ++i_) {                          \
      if (w_[2 * i_ + 1] != 0u) { is64_ = 0; break; }          \
    }                                                          \
    s_is64 = is64_;                                            \
  }                                                            \
  __syncthreads();

#define EDGE_GRID 4096
#define EDGE_BLOCK 256
#define SCAN_CHUNKS 8192

// ---------------------------------------------------------------------------
// Kernel 0: convert edge_index (int32 or int64) -> compact int32 src/dst.
// One pass; downstream kernels re-read the 4B arrays (r16 lesson: hist/place
// re-read the 8B int64 list 8x = ~200MB of avoidable traffic).
// ---------------------------------------------------------------------------
__global__ __launch_bounds__(256) void gin_convert(
    const void* __restrict__ edge_index, int* __restrict__ src32,
    int* __restrict__ dst32, int n_edges) {
  DETECT_IS64(edge_index);
  const int* ei32 = (const int*)edge_index;
  const long long* ei64 = (const long long*)edge_index;
  const int i = (int)(blockIdx.x * blockDim.x + threadIdx.x);
  const int stride = (int)(gridDim.x * blockDim.x);
  for (int e = i; e < n_edges; e += stride) {
    if (s_is64) {
      src32[e] = (int)ei64[e];
      dst32[e] = (int)ei64[n_edges + e];
    } else {
      src32[e] = ei32[e];
      dst32[e] = ei32[n_edges + e];
    }
  }
}

// ---------------------------------------------------------------------------
// Kernel 1: RANGE-FILTERED histogram over dst32 (node-major C, XCD-local
// atomics). Blocks with (b&7)==r own node range r and scan all of dst32.
// ---------------------------------------------------------------------------
__global__ __launch_bounds__(256) void gin_hist_ranged32(
    const int* __restrict__ dst32, int* __restrict__ C,
    int n_edges, int n_nodes) {
  const int r = (int)(blockIdx.x & (NGROUP - 1));
  const int nlo = (int)(((long long)n_nodes * r) / NGROUP);
  const int nhi = (int)(((long long)n_nodes * (r + 1)) / NGROUP);
  const int i = (int)((blockIdx.x >> 3) * blockDim.x + threadIdx.x);
  const int stride = (int)((gridDim.x >> 3) * blockDim.x);
  for (int e = i; e < n_edges; e += stride) {
    const int dst = dst32[e];
    if (dst >= nlo && dst < nhi) atomicAdd(&C[dst], 1);
  }
}

// ---------------------------------------------------------------------------
// Kernels 2a/2b/2c: in-place exclusive scan of C[total], SCAN_CHUNKS chunks.
// ---------------------------------------------------------------------------
__global__ __launch_bounds__(256) void gin_scan_a(
    const int* __restrict__ C, int* __restrict__ tsum, int total, int chunk) {
  const int t = (int)(blockIdx.x * blockDim.x + threadIdx.x);
  if (t >= SCAN_CHUNKS) return;
  const int beg = t * chunk;
  const int end = min(beg + chunk, total);
  int s = 0;
  for (int i = beg; i < end; ++i) s += C[i];
  tsum[t] = s;
}

__global__ __launch_bounds__(1024) void gin_scan_b(int* __restrict__ tsum) {
  __shared__ int ls[1024];
  const int t = threadIdx.x;
  int v[8];
  int s = 0;
#pragma unroll
  for (int i = 0; i < 8; ++i) {
    v[i] = tsum[t * 8 + i];
    s += v[i];
  }
  ls[t] = s;
  __syncthreads();
  for (int o = 1; o < 1024; o <<= 1) {
    const int a = (t >= o) ? ls[t - o] : 0;
    __syncthreads();
    ls[t] += a;
    __syncthreads();
  }
  int run = ls[t] - s;
#pragma unroll
  for (int i = 0; i < 8; ++i) {
    tsum[t * 8 + i] = run;
    run += v[i];
  }
}

__global__ __launch_bounds__(256) void gin_scan_c(
    int* __restrict__ C, const int* __restrict__ tsum, int total, int chunk) {
  const int t = (int)(blockIdx.x * blockDim.x + threadIdx.x);
  if (t >= SCAN_CHUNKS) return;
  const int beg = t * chunk;
  const int end = min(beg + chunk, total);
  int run = tsum[t];
  for (int i = beg; i < end; ++i) {
    const int c = C[i];
    C[i] = run;
    run += c;
  }
}

// ---------------------------------------------------------------------------
// Kernel 3: RANGE-FILTERED placement from int32 arrays.
// After this kernel, C[k] = prefix[k+1] (segment END of node k).
// ---------------------------------------------------------------------------
__global__ __launch_bounds__(256) void gin_place_ranged32(
    const int* __restrict__ src32, const int* __restrict__ dst32,
    int* __restrict__ C, int* __restrict__ sorted_src,
    int n_edges, int n_nodes) {
  const int r = (int)(blockIdx.x & (NGROUP - 1));
  const int nlo = (int)(((long long)n_nodes * r) / NGROUP);
  const int nhi = (int)(((long long)n_nodes * (r + 1)) / NGROUP);
  const int i = (int)((blockIdx.x >> 3) * blockDim.x + threadIdx.x);
  const int stride = (int)((gridDim.x >> 3) * blockDim.x);
  for (int e = i; e < n_edges; e += stride) {
    const int dst = dst32[e];
    if (dst >= nlo && dst < nhi) {
      const int pos = atomicAdd(&C[dst], 1);
      sorted_src[pos] = src32[e];
    }
  }
}

// ---------------------------------------------------------------------------
// Kernel 3.5: per-chunk segment-start lookup (removes the 17-step dependent
// binary-search chain from every gather wave; r16 profile: gather latency-
// bound at 51% occupancy).  cs[w] = first k with C[k] > w*CHUNK.
// ---------------------------------------------------------------------------
__global__ __launch_bounds__(256) void gin_chunkstart(
    const int* __restrict__ C, int* __restrict__ cs, int n_nodes,
    int nchunks) {
  const int t = (int)(blockIdx.x * blockDim.x + threadIdx.x);
  if (t >= nchunks) return;
  const int start = t * CHUNK;
  int lo = 0, hi = n_nodes - 1;
  while (lo < hi) {
    const int mid = (lo + hi) >> 1;
    if (C[mid] > start) hi = mid; else lo = mid + 1;
  }
  cs[t] = lo;
}

// ---------------------------------------------------------------------------
// Kernel 4: FLAT segmented-sum gather, CHUNK=32, precomputed chunk starts.
// One wave per 32 consecutive sorted entries; lane = feature. srcs staged
// into SGPRs (readfirstlane), 32 independent 256B row reads in flight.
// Interior segments plain-store; boundary segments atomicAdd (agg
// pre-zeroed; degree-0 nodes stay zero).
// ---------------------------------------------------------------------------
__global__ __launch_bounds__(256) void gin_gather_flat(
    const float* __restrict__ x, const int* __restrict__ C,
    const int* __restrict__ sorted_src, const int* __restrict__ cs,
    float* __restrict__ agg, int n_nodes, int n_edges) {
  const int lane = (int)(threadIdx.x & 63);
  const int wave = (int)((blockIdx.x * blockDim.x + threadIdx.x) >> 6);
  const int start = wave * CHUNK;
  if (start >= n_edges) return;
  const int cend = min(start + CHUNK, n_edges);

  // stage sources into SGPRs (wave-uniform values)
  int srcs[CHUNK];
#pragma unroll
  for (int i = 0; i < CHUNK; ++i) {
    srcs[i] = __builtin_amdgcn_readfirstlane(
        sorted_src[min(start + i, n_edges - 1)]);
  }
  // stage rows: CHUNK independent coalesced 256B row-reads in flight
  float rows[CHUNK];
#pragma unroll
  for (int i = 0; i < CHUNK; ++i) {
    rows[i] = x[(size_t)srcs[i] * D + lane];
  }

  int k = cs[wave];
  int end = C[k];
  int segbeg = (k == 0) ? 0 : C[k - 1];

  float acc = 0.0f;
  int runstart = start;
#pragma unroll
  for (int i = 0; i < CHUNK; ++i) {
    const int pos = start + i;
    if (pos >= cend) break;  // tail chunk only
    acc += rows[i];
    if (pos + 1 == end) {
      const size_t off = (size_t)k * D + lane;
      if (segbeg >= start) {
        agg[off] = acc;               // interior: sole writer
      } else {
        atomicAdd(&agg[off], acc);    // crosses chunk start
      }
      acc = 0.0f;
      runstart = pos + 1;
      if (pos + 1 < cend) {
        segbeg = end;
        ++k;
        end = C[k];
        while (end == segbeg) { ++k; end = C[k]; }  // skip empty nodes
      }
    }
  }
  if (runstart < cend) {
    atomicAdd(&agg[(size_t)k * D + lane], acc);  // trailing open run
  }
}

// ---------------------------------------------------------------------------
// Mid-path fallback kernels (read edge_index directly; r16 behavior).
// ---------------------------------------------------------------------------
__global__ __launch_bounds__(256) void gin_hist_ranged(
    const void* __restrict__ edge_index, int* __restrict__ C,
    int n_edges, int n_nodes) {
  DETECT_IS64(edge_index);
  const int* ei32 = (const int*)edge_index;
  const long long* ei64 = (const long long*)edge_index;
  const int r = (int)(blockIdx.x & (NGROUP - 1));
  const int nlo = (int)(((long long)n_nodes * r) / NGROUP);
  const int nhi = (int)(((long long)n_nodes * (r + 1)) / NGROUP);
  const int i = (int)((blockIdx.x >> 3) * blockDim.x + threadIdx.x);
  const int stride = (int)((gridDim.x >> 3) * blockDim.x);
  for (int e = i; e < n_edges; e += stride) {
    const int dst = s_is64 ? (int)ei64[n_edges + e] : ei32[n_edges + e];
    if (dst >= nlo && dst < nhi) atomicAdd(&C[dst], 1);
  }
}

__global__ __launch_bounds__(256) void gin_place_ranged(
    const void* __restrict__ edge_index, int* __restrict__ C,
    int* __restrict__ sorted_src, int n_edges, int n_nodes) {
  DETECT_IS64(edge_index);
  const int* ei32 = (const int*)edge_index;
  const long long* ei64 = (const long long*)edge_index;
  const int r = (int)(blockIdx.x & (NGROUP - 1));
  const int nlo = (int)(((long long)n_nodes * r) / NGROUP);
  const int nhi = (int)(((long long)n_nodes * (r + 1)) / NGROUP);
  const int i = (int)((blockIdx.x >> 3) * blockDim.x + threadIdx.x);
  const int stride = (int)((gridDim.x >> 3) * blockDim.x);
  for (int e = i; e < n_edges; e += stride) {
    const int dst = s_is64 ? (int)ei64[n_edges + e] : ei32[n_edges + e];
    if (dst >= nlo && dst < nhi) {
      const int src = s_is64 ? (int)ei64[e] : ei32[e];
      const int pos = atomicAdd(&C[dst], 1);
      sorted_src[pos] = src;
    }
  }
}

// ---------------------------------------------------------------------------
// Last-resort fallback scatter: scalar float atomics, wave per edge.
// ---------------------------------------------------------------------------
__global__ __launch_bounds__(256) void gin_scatter_atomic(
    const float* __restrict__ x, const void* __restrict__ edge_index,
    float* __restrict__ agg, int n_edges) {
  DETECT_IS64(edge_index);
  const int* ei32 = (const int*)edge_index;
  const long long* ei64 = (const long long*)edge_index;
  const int lane = threadIdx.x & 63;
  int wave = (int)((blockIdx.x * blockDim.x + threadIdx.x) >> 6);
  const int nwaves = (int)((gridDim.x * blockDim.x) >> 6);
  for (int e = wave; e < n_edges; e += nwaves) {
    int src, dst;
    if (s_is64) {
      src = (int)ei64[e];
      dst = (int)ei64[n_edges + e];
    } else {
      src = ei32[e];
      dst = ei32[n_edges + e];
    }
    atomicAdd(&agg[(size_t)dst * D + lane], x[(size_t)src * D + lane]);
  }
}

// ---------------------------------------------------------------------------
// Kernel 5: block-tiled MLP (vector f32 GEMM). Unchanged from round 10/11.
// ---------------------------------------------------------------------------
__global__ __launch_bounds__(256) void gin_mlp_tiled(
    const float* __restrict__ x,
    const float* __restrict__ agg_in,
    const float* __restrict__ eps_p,
    const float* __restrict__ W1, const float* __restrict__ b1,
    const float* __restrict__ W2, const float* __restrict__ b2,
    float* __restrict__ out,
    int n_nodes) {
  __shared__ float zs[128 * 72];   // z tile; reused for h
  __shared__ float w1s[64 * 64];
  __shared__ float w2s[64 * 64];

  const int t = (int)threadIdx.x;
  const int base = (int)blockIdx.x * 128;
  const float scale = 1.0f + eps_p[0];

  {
    const float4* W1v = (const float4*)W1;
    const float4* W2v = (const float4*)W2;
#pragma unroll
    for (int i = 0; i < 4; ++i) {
      const int idx = t + 256 * i;
      const int j = idx >> 4;
      const int kq = idx & 15;
      const int slot = kq ^ ((j >> 2) & 7);
      *(float4*)&w1s[j * 64 + slot * 4] = W1v[idx];
      *(float4*)&w2s[j * 64 + slot * 4] = W2v[idx];
    }
  }

  {
#pragma unroll
    for (int i = 0; i < 8; ++i) {
      const int idx = t + 256 * i;
      const int row = idx >> 4;
      const int kq = idx & 15;
      const int g = base + row;
      float4 zv;
      zv.x = 0.0f; zv.y = 0.0f; zv.z = 0.0f; zv.w = 0.0f;
      if (g < n_nodes) {
        const float4 xv = *(const float4*)(x + (size_t)g * D + kq * 4);
        const float4 av = *(const float4*)(agg_in + (size_t)g * D + kq * 4);
        zv.x = scale * xv.x + av.x;
        zv.y = scale * xv.y + av.y;
        zv.z = scale * xv.z + av.z;
        zv.w = scale * xv.w + av.w;
      }
      *(float4*)&zs[row * 72 + kq * 4] = zv;
    }
  }
  __syncthreads();

  const int jg = t & 15;
  const int mg = t >> 4;
  const float4 b1q = ((const float4*)b1)[jg];
  const float4 b2q = ((const float4*)b2)[jg];
  const int wswz = (jg & 7);

  float acc[8][4];
#pragma unroll
  for (int r = 0; r < 8; ++r) {
    acc[r][0] = b1q.x; acc[r][1] = b1q.y;
    acc[r][2] = b1q.z; acc[r][3] = b1q.w;
  }

#pragma unroll 4
  for (int kq = 0; kq < 16; ++kq) {
    float4 wq[4];
#pragma unroll
    for (int c = 0; c < 4; ++c) {
      wq[c] = *(const float4*)&w1s[(4 * jg + c) * 64 + ((kq ^ wswz) * 4)];
    }
#pragma unroll
    for (int r = 0; r < 8; ++r) {
      const float4 zq = *(const float4*)&zs[(r * 16 + mg) * 72 + kq * 4];
#pragma unroll
      for (int c = 0; c < 4; ++c) {
        acc[r][c] += zq.x * wq[c].x + zq.y * wq[c].y +
                     zq.z * wq[c].z + zq.w * wq[c].w;
      }
    }
  }

  __syncthreads();
#pragma unroll
  for (int r = 0; r < 8; ++r) {
    float4 hv;
    hv.x = fmaxf(acc[r][0], 0.0f);
    hv.y = fmaxf(acc[r][1], 0.0f);
    hv.z = fmaxf(acc[r][2], 0.0f);
    hv.w = fmaxf(acc[r][3], 0.0f);
    *(float4*)&zs[(r * 16 + mg) * 72 + jg * 4] = hv;
  }
  __syncthreads();

#pragma unroll
  for (int r = 0; r < 8; ++r) {
    acc[r][0] = b2q.x; acc[r][1] = b2q.y;
    acc[r][2] = b2q.z; acc[r][3] = b2q.w;
  }
#pragma unroll 4
  for (int kq = 0; kq < 16; ++kq) {
    float4 wq[4];
#pragma unroll
    for (int c = 0; c < 4; ++c) {
      wq[c] = *(const float4*)&w2s[(4 * jg + c) * 64 + ((kq ^ wswz) * 4)];
    }
#pragma unroll
    for (int r = 0; r < 8; ++r) {
      const float4 zq = *(const float4*)&zs[(r * 16 + mg) * 72 + kq * 4];
#pragma unroll
      for (int c = 0; c < 4; ++c) {
        acc[r][c] += zq.x * wq[c].x + zq.y * wq[c].y +
                     zq.z * wq[c].z + zq.w * wq[c].w;
      }
    }
  }

#pragma unroll
  for (int r = 0; r < 8; ++r) {
    const int g = base + r * 16 + mg;
    if (g < n_nodes) {
      float4 ov;
      ov.x = acc[r][0]; ov.y = acc[r][1];
      ov.z = acc[r][2]; ov.w = acc[r][3];
      *(float4*)(out + (size_t)g * D + jg * 4) = ov;
    }
  }
}

extern "C" void kernel_launch(void* const* d_in, const int* in_sizes, int n_in,
                              void* d_out, int out_size, void* d_ws, size_t ws_size,
                              hipStream_t stream) {
  const float* x   = (const float*)d_in[0];
  const void*  ei  = d_in[1];
  const float* eps = (const float*)d_in[2];
  const float* W1  = (const float*)d_in[3];
  const float* b1  = (const float*)d_in[4];
  const float* W2  = (const float*)d_in[5];
  const float* b2  = (const float*)d_in[6];
  float* out = (float*)d_out;

  const int n_nodes = in_sizes[0] / D;
  const int n_edges = in_sizes[1] / 2;
  const int nchunks = (n_edges + CHUNK - 1) / CHUNK;

  // ws layouts (ints):
  //  full: C[n] | tsum | sorted[E] | cs[nchunks] | src32[E] | dst32[E]
  //  mid:  C[n] | tsum | sorted[E] | cs[nchunks]
  const size_t base_ints =
      (size_t)n_nodes + SCAN_CHUNKS + (size_t)n_edges + (size_t)nchunks;
  const size_t need_full = (base_ints + 2 * (size_t)n_edges) * 4;
  const size_t need_mid = base_ints * 4;

  if (ws_size >= need_mid) {
    int* C      = (int*)d_ws;
    int* tsum   = C + n_nodes;
    int* sorted = tsum + SCAN_CHUNKS;
    int* cs     = sorted + n_edges;
    int* src32  = cs + nchunks;
    int* dst32  = src32 + n_edges;
    const bool full = (ws_size >= need_full);

    (void)hipMemsetAsync(C, 0, (size_t)n_nodes * 4, stream);
    // agg (= out) pre-zeroed: flat gather atomic-flushes boundary runs and
    // leaves degree-0 rows untouched.
    (void)hipMemsetAsync(out, 0, (size_t)n_nodes * D * sizeof(float), stream);

    if (full) {
      gin_convert<<<EDGE_GRID, EDGE_BLOCK, 0, stream>>>(ei, src32, dst32,
                                                        n_edges);
      gin_hist_ranged32<<<EDGE_GRID, EDGE_BLOCK, 0, stream>>>(dst32, C,
                                                              n_edges,
                                                              n_nodes);
    } else {
      gin_hist_ranged<<<EDGE_GRID, EDGE_BLOCK, 0, stream>>>(ei, C, n_edges,
                                                            n_nodes);
    }

    const int chunk = (n_nodes + SCAN_CHUNKS - 1) / SCAN_CHUNKS;
    gin_scan_a<<<SCAN_CHUNKS / 256, 256, 0, stream>>>(C, tsum, n_nodes,
                                                      chunk);
    gin_scan_b<<<1, 1024, 0, stream>>>(tsum);
    gin_scan_c<<<SCAN_CHUNKS / 256, 256, 0, stream>>>(C, tsum, n_nodes,
                                                      chunk);

    if (full) {
      gin_place_ranged32<<<EDGE_GRID, EDGE_BLOCK, 0, stream>>>(
          src32, dst32, C, sorted, n_edges, n_nodes);
    } else {
      gin_place_ranged<<<EDGE_GRID, EDGE_BLOCK, 0, stream>>>(ei, C, sorted,
                                                             n_edges,
                                                             n_nodes);
    }

    gin_chunkstart<<<(nchunks + 255) / 256, 256, 0, stream>>>(C, cs, n_nodes,
                                                              nchunks);

    const int gather_blocks = (nchunks + 3) / 4;  // 4 waves per block
    gin_gather_flat<<<gather_blocks, 256, 0, stream>>>(x, C, sorted, cs, out,
                                                       n_nodes, n_edges);
  } else {
    (void)hipMemsetAsync(out, 0, (size_t)n_nodes * D * sizeof(float), stream);
    gin_scatter_atomic<<<4096, 256, 0, stream>>>(x, ei, out, n_edges);
  }

  const int mlp_blocks = (n_nodes + 127) / 128;
  gin_mlp_tiled<<<mlp_blocks, 256, 0, stream>>>(x, out, eps, W1, b1, W2, b2,
                                                out, n_nodes);
}